// Round 3
// baseline (1032.132 us; speedup 1.0000x reference)
//
#include <hip/hip_runtime.h>
#include <stdint.h>

#define T_TOK 8192
#define H_DIM 1024
#define I_DIM 2752
#define E_NUM 8

typedef unsigned short ushort_t;
typedef short bf16x8 __attribute__((ext_vector_type(8)));
typedef float f32x4 __attribute__((ext_vector_type(4)));

__device__ __forceinline__ unsigned short f2bf(float f){
  union { float f; uint32_t u; } v; v.f = f;
  return (unsigned short)((v.u + 0x7fffu + ((v.u >> 16) & 1u)) >> 16);
}

// async global -> LDS, 16B per lane; lds dest = wave-uniform base + lane*16
__device__ __forceinline__ void gload16(const ushort_t* g, ushort_t* l){
  __builtin_amdgcn_global_load_lds(
      (const __attribute__((address_space(1))) void*)g,
      (__attribute__((address_space(3))) void*)l, 16, 0, 0);
}

// ---------------- convert fp32 -> bf16 ----------------
__global__ void cvt_kernel(const float4* __restrict__ src, ushort4* __restrict__ dst, int n4){
  int stride = gridDim.x * blockDim.x;
  for (int i = blockIdx.x * blockDim.x + threadIdx.x; i < n4; i += stride){
    float4 v = src[i];
    ushort4 o;
    o.x = f2bf(v.x); o.y = f2bf(v.y); o.z = f2bf(v.z); o.w = f2bf(v.w);
    dst[i] = o;
  }
}

__global__ void fill_kernel(float* __restrict__ p, float v, int n){
  int i = blockIdx.x * blockDim.x + threadIdx.x;
  if (i < n) p[i] = v;
}

// ---------------- gate: fp32 logits, softmax-top2; also emits x in bf16 ----------------
__global__ void gate_kernel(const float* __restrict__ x, const float* __restrict__ gw,
                            ushort_t* __restrict__ xb,
                            int* __restrict__ topk_idx, float* __restrict__ topk_w,
                            int* __restrict__ counts){
  int lane = threadIdx.x & 63;
  int wv = threadIdx.x >> 6;
  int t = blockIdx.x * 4 + wv;
  const float* xt = x + (size_t)t * H_DIM;
  ushort_t* xbt = xb + (size_t)t * H_DIM;
  float acc[E_NUM];
  #pragma unroll
  for (int e = 0; e < E_NUM; e++) acc[e] = 0.f;
  for (int c = 0; c < H_DIM / 64; c++){
    float xv = xt[c * 64 + lane];
    xbt[c * 64 + lane] = f2bf(xv);
    #pragma unroll
    for (int e = 0; e < E_NUM; e++) acc[e] += xv * gw[e * H_DIM + c * 64 + lane];
  }
  #pragma unroll
  for (int e = 0; e < E_NUM; e++){
    #pragma unroll
    for (int o = 32; o; o >>= 1) acc[e] += __shfl_xor(acc[e], o);
  }
  if (lane == 0){
    int i1 = 0; float l1 = acc[0];
    #pragma unroll
    for (int e = 1; e < E_NUM; e++) if (acc[e] > l1){ l1 = acc[e]; i1 = e; }
    int i2 = -1; float l2 = -1e30f;
    #pragma unroll
    for (int e = 0; e < E_NUM; e++) if (e != i1 && acc[e] > l2){ l2 = acc[e]; i2 = e; }
    float e2 = expf(l2 - l1);
    float denom = 1.0f + e2;
    topk_idx[t * 2 + 0] = i1; topk_idx[t * 2 + 1] = i2;
    topk_w[t * 2 + 0] = 1.0f / denom; topk_w[t * 2 + 1] = e2 / denom;
    atomicAdd(&counts[i1], 1); atomicAdd(&counts[i2], 1);
  }
}

__global__ void offsets_kernel(const int* __restrict__ counts, int* __restrict__ offs,
                               int* __restrict__ cursor){
  if (threadIdx.x == 0 && blockIdx.x == 0){
    int a = 0;
    for (int e = 0; e < E_NUM; e++){ offs[e] = a; cursor[e] = a; a += counts[e]; }
    offs[E_NUM] = a;
  }
}

__global__ void scatter_kernel(const int* __restrict__ topk_idx, const float* __restrict__ topk_w,
                               int* __restrict__ cursor, int* __restrict__ perm,
                               float* __restrict__ pw){
  int t = blockIdx.x * blockDim.x + threadIdx.x;
  if (t >= T_TOK) return;
  #pragma unroll
  for (int k = 0; k < 2; k++){
    int e = topk_idx[t * 2 + k];
    int pos = atomicAdd(&cursor[e], 1);
    perm[pos] = t;
    pw[pos] = topk_w[t * 2 + k];
  }
}

// ---------------- GEMM1: h = silu(X@Wg^T) * (X@Wu^T) * route_w ----------------
// m97 structure: 128x128 tile, BK=64, 4 waves 2x2, global_load_lds width=16,
// linear [128][64] LDS tiles, 2-barrier K-loop.
__global__ __launch_bounds__(256, 2) void gemm1_kernel(
    const ushort_t* __restrict__ Xb,
    const ushort_t* __restrict__ Wg,
    const ushort_t* __restrict__ Wu,
    ushort_t* __restrict__ Hb,
    const int* __restrict__ offs,   // null => single "expert" (shared) of fixedM rows
    const int* __restrict__ perm,   // null => identity
    const float* __restrict__ pw,   // null => weight 1
    int fixedM)
{
  __shared__ __align__(16) ushort_t ldsA[128 * 64];
  __shared__ __align__(16) ushort_t ldsG[128 * 64];
  __shared__ __align__(16) ushort_t ldsU[128 * 64];

  const int tid = threadIdx.x;
  const int lane = tid & 63;
  const int wv = tid >> 6;
  const int wr = wv >> 1;
  const int wc = wv & 1;

  int e = 0, row0 = 0, mEnd = fixedM, maxRow = fixedM - 1;
  if (offs){
    int bx = blockIdx.x, base = 0;
    bool found = false;
    for (e = 0; e < E_NUM; ++e){
      int m0 = offs[e], m1 = offs[e + 1];
      int nt = (m1 - m0 + 127) >> 7;
      if (bx < base + nt){ row0 = m0 + (bx - base) * 128; mEnd = m1; found = true; break; }
      base += nt;
    }
    if (!found) return;
    maxRow = offs[E_NUM] - 1;
  } else {
    row0 = blockIdx.x * 128;
  }

  const ushort_t* Weg = Wg + (size_t)e * I_DIM * H_DIM;
  const ushort_t* Weu = Wu + (size_t)e * I_DIM * H_DIM;
  const int nb = blockIdx.y * 128;

  // staging: per wave 4 issues each for A/G/U; lane -> row (lane>>3), col (lane&7)*8
  const int lrow = lane >> 3;
  const int lcol = (lane & 7) << 3;

  const ushort_t* srcA[4];
  const ushort_t* srcG[4];
  const ushort_t* srcU[4];
  #pragma unroll
  for (int j = 0; j < 4; j++){
    int gr = row0 + wv * 32 + j * 8 + lrow;
    if (gr > maxRow) gr = maxRow;
    int tok = perm ? perm[gr] : gr;
    srcA[j] = Xb + (size_t)tok * H_DIM + lcol;
    int n = nb + wv * 32 + j * 8 + lrow;
    if (n > I_DIM - 1) n = I_DIM - 1;
    srcG[j] = Weg + (size_t)n * H_DIM + lcol;
    srcU[j] = Weu + (size_t)n * H_DIM + lcol;
  }

  f32x4 accg[4][4], accu[4][4];
  const f32x4 zero = {0.f, 0.f, 0.f, 0.f};
  #pragma unroll
  for (int m = 0; m < 4; m++)
    #pragma unroll
    for (int n = 0; n < 4; n++){ accg[m][n] = zero; accu[m][n] = zero; }

  const ushort_t* pA = ldsA + ((wr * 64 + (lane & 15)) * 64 + ((lane >> 4) << 3));
  const ushort_t* pG = ldsG + ((wc * 64 + (lane & 15)) * 64 + ((lane >> 4) << 3));
  const ushort_t* pU = ldsU + ((wc * 64 + (lane & 15)) * 64 + ((lane >> 4) << 3));

  for (int k0 = 0; k0 < H_DIM; k0 += 64){
    __syncthreads();                  // previous compute done: LDS free
    #pragma unroll
    for (int j = 0; j < 4; j++){
      gload16(srcA[j] + k0, ldsA + (wv * 32 + j * 8) * 64);
      gload16(srcG[j] + k0, ldsG + (wv * 32 + j * 8) * 64);
      gload16(srcU[j] + k0, ldsU + (wv * 32 + j * 8) * 64);
    }
    __syncthreads();                  // vmcnt(0) drained by barrier: tile ready
    #pragma unroll
    for (int ks = 0; ks < 2; ks++){
      bf16x8 a[4], bg[4], bu[4];
      #pragma unroll
      for (int m = 0; m < 4; m++) a[m]  = *(const bf16x8*)(pA + m * 16 * 64 + ks * 32);
      #pragma unroll
      for (int n = 0; n < 4; n++) bg[n] = *(const bf16x8*)(pG + n * 16 * 64 + ks * 32);
      #pragma unroll
      for (int n = 0; n < 4; n++) bu[n] = *(const bf16x8*)(pU + n * 16 * 64 + ks * 32);
      #pragma unroll
      for (int m = 0; m < 4; m++)
        #pragma unroll
        for (int n = 0; n < 4; n++){
          accg[m][n] = __builtin_amdgcn_mfma_f32_16x16x32_bf16(a[m], bg[n], accg[m][n], 0, 0, 0);
          accu[m][n] = __builtin_amdgcn_mfma_f32_16x16x32_bf16(a[m], bu[n], accu[m][n], 0, 0, 0);
        }
    }
  }

  // epilogue: silu(g)*u*wt -> bf16 h
  #pragma unroll
  for (int m = 0; m < 4; m++){
    #pragma unroll
    for (int j = 0; j < 4; j++){
      int gr = row0 + wr * 64 + m * 16 + ((lane >> 4) << 2) + j;
      if (gr < mEnd){
        float wt = pw ? pw[gr] : 1.0f;
        ushort_t* hrow = Hb + (size_t)gr * I_DIM;
        #pragma unroll
        for (int n = 0; n < 4; n++){
          int c = nb + wc * 64 + n * 16 + (lane & 15);
          if (c < I_DIM){
            float gv = accg[m][n][j];
            float uv = accu[m][n][j];
            float hv = (gv / (1.0f + __expf(-gv))) * uv * wt;
            hrow[c] = f2bf(hv);
          }
        }
      }
    }
  }
}

// ---------------- GEMM2: y[tok] (+)= h @ Wd^T ----------------
__global__ __launch_bounds__(256, 2) void gemm2_kernel(
    const ushort_t* __restrict__ Hb,
    const ushort_t* __restrict__ Wd,   // [H_DIM, I_DIM] per expert (bf16)
    float* __restrict__ Y,
    const int* __restrict__ offs,
    const int* __restrict__ perm,
    int fixedM, int doAtomic)
{
  __shared__ __align__(16) ushort_t ldsA[128 * 64];
  __shared__ __align__(16) ushort_t ldsB[128 * 64];

  const int tid = threadIdx.x;
  const int lane = tid & 63;
  const int wv = tid >> 6;
  const int wr = wv >> 1;
  const int wc = wv & 1;

  int e = 0, row0 = 0, mEnd = fixedM, maxRow = fixedM - 1;
  if (offs){
    int bx = blockIdx.x, base = 0;
    bool found = false;
    for (e = 0; e < E_NUM; ++e){
      int m0 = offs[e], m1 = offs[e + 1];
      int nt = (m1 - m0 + 127) >> 7;
      if (bx < base + nt){ row0 = m0 + (bx - base) * 128; mEnd = m1; found = true; break; }
      base += nt;
    }
    if (!found) return;
    maxRow = offs[E_NUM] - 1;
  } else {
    row0 = blockIdx.x * 128;
  }

  const ushort_t* Wde = Wd + (size_t)e * H_DIM * I_DIM;
  const int nb = blockIdx.y * 128;          // N = H_DIM = 1024, exact tiles

  const int lrow = lane >> 3;
  const int lcol = (lane & 7) << 3;

  const ushort_t* srcA[4];
  const ushort_t* srcB[4];
  #pragma unroll
  for (int j = 0; j < 4; j++){
    int gr = row0 + wv * 32 + j * 8 + lrow;
    if (gr > maxRow) gr = maxRow;
    srcA[j] = Hb + (size_t)gr * I_DIM + lcol;
    int n = nb + wv * 32 + j * 8 + lrow;
    srcB[j] = Wde + (size_t)n * I_DIM + lcol;
  }

  f32x4 acc[4][4];
  const f32x4 zero = {0.f, 0.f, 0.f, 0.f};
  #pragma unroll
  for (int m = 0; m < 4; m++)
    #pragma unroll
    for (int n = 0; n < 4; n++) acc[m][n] = zero;

  const ushort_t* pA = ldsA + ((wr * 64 + (lane & 15)) * 64 + ((lane >> 4) << 3));
  const ushort_t* pB = ldsB + ((wc * 64 + (lane & 15)) * 64 + ((lane >> 4) << 3));

  for (int k0 = 0; k0 < I_DIM; k0 += 64){   // 2752 = 43 * 64, exact
    __syncthreads();
    #pragma unroll
    for (int j = 0; j < 4; j++){
      gload16(srcA[j] + k0, ldsA + (wv * 32 + j * 8) * 64);
      gload16(srcB[j] + k0, ldsB + (wv * 32 + j * 8) * 64);
    }
    __syncthreads();
    #pragma unroll
    for (int ks = 0; ks < 2; ks++){
      bf16x8 a[4], b[4];
      #pragma unroll
      for (int m = 0; m < 4; m++) a[m] = *(const bf16x8*)(pA + m * 16 * 64 + ks * 32);
      #pragma unroll
      for (int n = 0; n < 4; n++) b[n] = *(const bf16x8*)(pB + n * 16 * 64 + ks * 32);
      #pragma unroll
      for (int m = 0; m < 4; m++)
        #pragma unroll
        for (int n = 0; n < 4; n++)
          acc[m][n] = __builtin_amdgcn_mfma_f32_16x16x32_bf16(a[m], b[n], acc[m][n], 0, 0, 0);
    }
  }

  #pragma unroll
  for (int m = 0; m < 4; m++){
    #pragma unroll
    for (int j = 0; j < 4; j++){
      int gr = row0 + wr * 64 + m * 16 + ((lane >> 4) << 2) + j;
      if (gr < mEnd){
        int tok = perm ? perm[gr] : gr;
        float* yrow = Y + (size_t)tok * H_DIM;
        #pragma unroll
        for (int n = 0; n < 4; n++){
          int c = nb + wc * 64 + n * 16 + (lane & 15);
          float v = acc[m][n][j];
          if (doAtomic) atomicAdd(&yrow[c], v);
          else          yrow[c] = v;
        }
      }
    }
  }
}

// ---------------- launch ----------------
extern "C" void kernel_launch(void* const* d_in, const int* in_sizes, int n_in,
                              void* d_out, int out_size, void* d_ws, size_t ws_size,
                              hipStream_t stream) {
  const float* x      = (const float*)d_in[0];
  const float* gate_w = (const float*)d_in[1];
  const float* wg     = (const float*)d_in[2];
  const float* wu     = (const float*)d_in[3];
  const float* wd     = (const float*)d_in[4];
  const float* swg    = (const float*)d_in[5];
  const float* swu    = (const float*)d_in[6];
  const float* swd    = (const float*)d_in[7];
  float* Y = (float*)d_out;
  char* ws = (char*)d_ws;

  constexpr size_t XB_SZ   = (size_t)T_TOK * H_DIM * 2;            // 16,777,216
  constexpr size_t WEXP_SZ = (size_t)E_NUM * I_DIM * H_DIM * 2;    // 45,088,768
  constexpr size_t SW_SZ   = (size_t)I_DIM * H_DIM * 2;            //  5,636,096
  constexpr size_t H_SZ    = (size_t)T_TOK * 2 * I_DIM * 2;        // 90,177,536

  constexpr size_t XB_OFF  = 0;
  constexpr size_t WG_OFF  = XB_OFF + XB_SZ;
  constexpr size_t WU_OFF  = WG_OFF + WEXP_SZ;
  constexpr size_t WD_OFF  = WU_OFF + WEXP_SZ;
  constexpr size_t SWG_OFF = WD_OFF + WEXP_SZ;
  constexpr size_t SWU_OFF = SWG_OFF + SW_SZ;
  constexpr size_t SWD_OFF = SWU_OFF + SW_SZ;
  constexpr size_t H_OFF   = SWD_OFF + SW_SZ;
  constexpr size_t META_OFF = H_OFF + H_SZ;
  constexpr size_t TI_OFF  = META_OFF;            // topk_idx: 16384 int
  constexpr size_t TW_OFF  = TI_OFF + 65536;      // topk_w
  constexpr size_t PM_OFF  = TW_OFF + 65536;      // perm
  constexpr size_t PW_OFF  = PM_OFF + 65536;      // pw
  constexpr size_t CNT_OFF = PW_OFF + 65536;      // counts(8) offs(9) cursor(8)
  constexpr size_t NEEDED  = CNT_OFF + 4096;

  if (ws_size < NEEDED){
    fill_kernel<<<(out_size + 255) / 256, 256, 0, stream>>>(Y, 12345.0f, out_size);
    return;
  }

  ushort_t* xb   = (ushort_t*)(ws + XB_OFF);
  ushort_t* wgb  = (ushort_t*)(ws + WG_OFF);
  ushort_t* wub  = (ushort_t*)(ws + WU_OFF);
  ushort_t* wdb  = (ushort_t*)(ws + WD_OFF);
  ushort_t* swgb = (ushort_t*)(ws + SWG_OFF);
  ushort_t* swub = (ushort_t*)(ws + SWU_OFF);
  ushort_t* swdb = (ushort_t*)(ws + SWD_OFF);
  ushort_t* hb   = (ushort_t*)(ws + H_OFF);
  int*   topk_idx = (int*)(ws + TI_OFF);
  float* topk_w   = (float*)(ws + TW_OFF);
  int*   perm     = (int*)(ws + PM_OFF);
  float* pw       = (float*)(ws + PW_OFF);
  int*   counts   = (int*)(ws + CNT_OFF);
  int*   offs     = counts + 8;
  int*   cursor   = offs + 9;

  // fp32 -> bf16 conversions (x handled inside gate_kernel)
  cvt_kernel<<<2048, 256, 0, stream>>>((const float4*)wg,  (ushort4*)wgb,  (int)(E_NUM * (size_t)I_DIM * H_DIM / 4));
  cvt_kernel<<<2048, 256, 0, stream>>>((const float4*)wu,  (ushort4*)wub,  (int)(E_NUM * (size_t)I_DIM * H_DIM / 4));
  cvt_kernel<<<2048, 256, 0, stream>>>((const float4*)wd,  (ushort4*)wdb,  (int)(E_NUM * (size_t)I_DIM * H_DIM / 4));
  cvt_kernel<<<1024, 256, 0, stream>>>((const float4*)swg, (ushort4*)swgb, (int)((size_t)I_DIM * H_DIM / 4));
  cvt_kernel<<<1024, 256, 0, stream>>>((const float4*)swu, (ushort4*)swub, (int)((size_t)I_DIM * H_DIM / 4));
  cvt_kernel<<<1024, 256, 0, stream>>>((const float4*)swd, (ushort4*)swdb, (int)((size_t)I_DIM * H_DIM / 4));

  hipMemsetAsync(counts, 0, 8 * sizeof(int), stream);
  gate_kernel<<<T_TOK / 4, 256, 0, stream>>>(x, gate_w, xb, topk_idx, topk_w, counts);
  offsets_kernel<<<1, 64, 0, stream>>>(counts, offs, cursor);
  scatter_kernel<<<T_TOK / 256, 256, 0, stream>>>(topk_idx, topk_w, cursor, perm, pw);

  // shared expert (writes y with '=', covering all of d_out)
  gemm1_kernel<<<dim3(T_TOK / 128, (I_DIM + 127) / 128), 256, 0, stream>>>(
      xb, swgb, swub, hb, nullptr, nullptr, nullptr, T_TOK);
  gemm2_kernel<<<dim3(T_TOK / 128, H_DIM / 128), 256, 0, stream>>>(
      hb, swdb, Y, nullptr, nullptr, T_TOK, 0);

  // routed experts (grouped GEMM over perm-ordered rows; atomicAdd combine)
  constexpr int MAX_TILES = (T_TOK * 2) / 128 + E_NUM;   // 136
  gemm1_kernel<<<dim3(MAX_TILES, (I_DIM + 127) / 128), 256, 0, stream>>>(
      xb, wgb, wub, hb, offs, perm, pw, 0);
  gemm2_kernel<<<dim3(MAX_TILES, H_DIM / 128), 256, 0, stream>>>(
      hb, wdb, Y, offs, perm, 0, 1);
}